// Round 1
// 608.800 us; speedup vs baseline: 1.0441x; 1.0441x over previous
//
#include <hip/hip_runtime.h>
#include <math.h>

#define RR 32
#define V 32768          // RR^3
#define C 240
#define N 16384
#define B 8
#define K2C 480          // 2*C
#define NG 2048          // V/GZ groups per batch
#define GZ 16            // voxels per column-group (z half-column)
#define FPAD 488         // fea_s row stride in ushorts (488/2=244 dwords = 4*61, odd multiple of 4)
#define EBUF 512         // staged point entries per round

typedef __attribute__((ext_vector_type(8))) short bf16x8;
typedef __attribute__((ext_vector_type(4))) float f32x4;

__device__ __forceinline__ unsigned short f2bf(float x) {
    unsigned u = __float_as_uint(x);
    u += 0x7fffu + ((u >> 16) & 1u);   // RNE, finite inputs
    return (unsigned short)(u >> 16);
}

// ---------- fused: wide hist zero + conv_w->bf16 (blocks 0..255) + per-batch stats (blocks 256..263) ----------
__global__ __launch_bounds__(256) void init_stats_kernel(const float* __restrict__ coords,
                                                         float* __restrict__ stats,
                                                         int* __restrict__ hist,
                                                         const float* __restrict__ w,
                                                         unsigned short* __restrict__ w_bf) {
    int blk = blockIdx.x;
    int tid = threadIdx.x;
    if (blk < 256) {
        int t = blk * 256 + tid;                 // 65536 threads
        int4 z4 = {0, 0, 0, 0};
        ((int4*)hist)[t] = z4;                   // B*V ints = 65536 int4 exactly
        if (t < 57600) {                         // 240*480/2 packed converts
            unsigned lo = f2bf(w[2 * t]);
            unsigned hi = f2bf(w[2 * t + 1]);
            ((unsigned*)w_bf)[t] = lo | (hi << 16);
        }
        return;
    }
    int b = blk - 256;
    const float* cb = coords + (size_t)b * 3 * N;
    __shared__ float red[256];
    float m[3];
    for (int d = 0; d < 3; ++d) {
        float s = 0.f;
        for (int n = tid; n < N; n += 256) s += cb[d * N + n];
        red[tid] = s; __syncthreads();
        for (int w2 = 128; w2 > 0; w2 >>= 1) { if (tid < w2) red[tid] += red[tid + w2]; __syncthreads(); }
        m[d] = red[0] / (float)N;
        __syncthreads();
    }
    float mx = 0.f;
    for (int n = tid; n < N; n += 256) {
        float dx = cb[0 * N + n] - m[0];
        float dy = cb[1 * N + n] - m[1];
        float dz = cb[2 * N + n] - m[2];
        mx = fmaxf(mx, dx * dx + dy * dy + dz * dz);
    }
    red[tid] = mx; __syncthreads();
    for (int w2 = 128; w2 > 0; w2 >>= 1) { if (tid < w2) red[tid] = fmaxf(red[tid], red[tid + w2]); __syncthreads(); }
    if (tid == 0) {
        stats[b * 4 + 0] = m[0];
        stats[b * 4 + 1] = m[1];
        stats[b * 4 + 2] = m[2];
        stats[b * 4 + 3] = 2.f * sqrtf(red[0]);
    }
}

// ---------- nc (output 2) + flat voxel idx + per-voxel histogram ----------
__global__ __launch_bounds__(256) void nc_idx_kernel(const float* __restrict__ coords,
                                                     const float* __restrict__ stats,
                                                     float* __restrict__ nc_out,
                                                     int* __restrict__ idxbuf,
                                                     int* __restrict__ hist) {
    int t = blockIdx.x * 256 + threadIdx.x;   // over B*N
    int b = t >> 14;
    int n = t & (N - 1);
    float denom = stats[b * 4 + 3];
    int v[3];
#pragma unroll
    for (int d = 0; d < 3; ++d) {
        float x = coords[((size_t)b * 3 + d) * N + n];
        float t0 = (x - stats[b * 4 + d]) / denom + 0.5f;
        t0 = t0 * (float)RR;
        t0 = fminf(fmaxf(t0, 0.f), (float)(RR - 1));
        nc_out[((size_t)b * 3 + d) * N + n] = t0;
        v[d] = (int)rintf(t0);   // round half to even == jnp.round
    }
    int iv = v[0] * (RR * RR) + v[1] * RR + v[2];
    idxbuf[t] = iv;
    atomicAdd(hist + b * V + iv, 1);
}

// ---------- exclusive prefix over V=32768 voxels per batch (int4 I/O) ----------
__global__ __launch_bounds__(1024) void prefix_kernel(const int* __restrict__ hist,
                                                      int* __restrict__ starts,
                                                      int* __restrict__ cursor) {
    __shared__ int part[1024];
    int b = blockIdx.x, t = threadIdx.x;
    int base = b * V + t * 32;
    const int4* hp = (const int4*)(hist + base);
    int4 h[8];
    int s = 0;
#pragma unroll
    for (int j = 0; j < 8; ++j) { h[j] = hp[j]; s += h[j].x + h[j].y + h[j].z + h[j].w; }
    part[t] = s; __syncthreads();
    for (int off = 1; off < 1024; off <<= 1) {
        int x = (t >= off) ? part[t - off] : 0;
        __syncthreads();
        part[t] += x;
        __syncthreads();
    }
    int run = part[t] - s;   // exclusive
    int4* sp = (int4*)(starts + base);
    int4* cp = (int4*)(cursor + base);
#pragma unroll
    for (int j = 0; j < 8; ++j) {
        int4 o;
        o.x = run; run += h[j].x;
        o.y = run; run += h[j].y;
        o.z = run; run += h[j].z;
        o.w = run; run += h[j].w;
        sp[j] = o; cp[j] = o;
    }
}

// ---------- scatter point ids into voxel-sorted order ----------
__global__ __launch_bounds__(256) void plist_kernel(const int* __restrict__ idxbuf,
                                                    int* __restrict__ cursor,
                                                    int* __restrict__ ptlist) {
    int t = blockIdx.x * 256 + threadIdx.x;   // over B*N
    int b = t >> 14;
    int n = t & (N - 1);
    int iv = idxbuf[t];
    int pos = atomicAdd(cursor + b * V + iv, 1);
    ptlist[(b << 14) + pos] = (n << 5) | (iv & 31);
}

// ---------- features [B][C][N] fp32 -> featT [B][N][C] bf16 ----------
__global__ __launch_bounds__(256) void transpose_kernel(const float* __restrict__ feat,
                                                        unsigned short* __restrict__ featT) {
    __shared__ float t[C][33];
    int b = blockIdx.y;
    int n0 = blockIdx.x * 32;
    int l = threadIdx.x;
    const float* fb = feat + (size_t)b * C * N;
    unsigned short* fTb = featT + (size_t)b * N * C;
    int nl = l & 31, cs = l >> 5;   // 8 c-rows per pass
#pragma unroll
    for (int p = 0; p < 30; ++p) {
        int c = p * 8 + cs;
        t[c][nl] = fb[(size_t)c * N + n0 + nl];
    }
    __syncthreads();
    int ci = l & 127;               // uint (2-channel) index, <120 active
    int nh = l >> 7;                // 2 n-rows per pass
#pragma unroll
    for (int p = 0; p < 16; ++p) {
        int n = 2 * p + nh;
        if (ci < 120) {
            unsigned lo = f2bf(t[2 * ci][n]);
            unsigned hi = f2bf(t[2 * ci + 1][n]);
            *(unsigned*)&fTb[(size_t)(n0 + n) * C + 2 * ci] = lo | (hi << 16);
        }
    }
}

// ---------- fused per-16-voxel-group pipelined reduce + bf16 MFMA + BN + swish ----------
// LDS ~19.7 KB -> 8 blocks/CU (was 4). Streaming: one channel per thread, 240/256 lanes
// active across all 4 waves (was 120 lanes on 2 waves).
__global__ __launch_bounds__(256) void column_kernel(
    const unsigned short* __restrict__ featT,   // [B][N][C] bf16
    const int* __restrict__ ptlist,
    const int* __restrict__ starts,
    const int* __restrict__ hist,
    const unsigned short* __restrict__ w_bf,    // [240][480] bf16
    const float* __restrict__ cbias, const float* __restrict__ gamma,
    const float* __restrict__ beta, const float* __restrict__ mean,
    const float* __restrict__ var,
    float* __restrict__ out) {
    const int g = blockIdx.x, b = blockIdx.y;
    const int tid = threadIdx.x;
    const int v0 = g * GZ;
    float* outb = out + (size_t)b * C * V;

    __shared__ float A_s[C], B_s[C], rcp_s[GZ];
    __shared__ unsigned short fea_s[GZ][FPAD];   // [z][k]: k<240 max, k>=240 avg (bf16)
    __shared__ int cnt_s[GZ];
    __shared__ int ebuf[EBUF];

    if (tid < C) {
        float sc = gamma[tid] * rsqrtf(var[tid] + 1e-5f);
        A_s[tid] = sc;
        B_s[tid] = (cbias[tid] - mean[tid]) * sc + beta[tid];
    }
    if (tid < GZ) {
        int c0 = hist[b * V + v0 + tid];
        cnt_s[tid] = c0;
        rcp_s[tid] = 1.f / (float)max(c0, 1);
    }
    __syncthreads();

    int pc = 0;
#pragma unroll
    for (int z = 0; z < GZ; ++z) pc += cnt_s[z];

    if (pc == 0) {   // empty group: constant output vector
        for (int i = tid; i < C * GZ; i += 256) {
            int o = i >> 4, vv = i & (GZ - 1);
            float y = B_s[o];
            y = y / (1.f + __expf(-y));
            outb[(size_t)o * V + v0 + vv] = y;
        }
        return;
    }

    // zero fea (covers empty voxels: max->0, avg->0)
    for (int i = tid; i < GZ * FPAD / 2; i += 256) ((unsigned*)fea_s)[i] = 0u;

    const int c = tid;             // one channel per thread
    const bool act = tid < C;
    const int pos = starts[b * V + v0];
    const int* pl = ptlist + (b << 14) + pos;
    const unsigned short* fT = featT + (size_t)b * N * C;

    // ---- pipelined 1-channel stream over all points (sorted by z) ----
    float s0 = 0.f, mx0 = -INFINITY;
    int curz = -1;
    for (int base = 0; base < pc; base += EBUF) {
        int mm = min(EBUF, pc - base);
        __syncthreads();
        for (int i = tid; i < mm; i += 256) ebuf[i] = pl[base + i];   // coalesced stage
        __syncthreads();
        if (act) {
            for (int i0 = 0; i0 < mm; i0 += 16) {
                int m = min(16, mm - i0);
                int e_[16];
#pragma unroll
                for (int j = 0; j < 16; ++j) e_[j] = ebuf[i0 + ((j < m) ? j : m - 1)];
                unsigned short u_[16];
#pragma unroll
                for (int j = 0; j < 16; ++j)
                    u_[j] = fT[(size_t)(e_[j] >> 5) * C + c];
#pragma unroll
                for (int j = 0; j < 16; ++j) {
                    if (j < m) {
                        int zj = e_[j] & (GZ - 1);       // z within this 16-group
                        if (zj != curz) {                // uniform branch
                            if (curz >= 0) {
                                fea_s[curz][c] = f2bf(mx0);
                                fea_s[curz][C + c] = f2bf(s0 * rcp_s[curz]);
                            }
                            curz = zj; s0 = 0.f; mx0 = -INFINITY;
                        }
                        float f = __uint_as_float(((unsigned)u_[j]) << 16);
                        s0 += f; mx0 = fmaxf(mx0, f);
                    }
                }
            }
        }
    }
    if (act && curz >= 0) {
        fea_s[curz][c] = f2bf(mx0);
        fea_s[curz][C + c] = f2bf(s0 * rcp_s[curz]);
    }
    __syncthreads();

    // ---- MFMA: D[o][z] = sum_k w[o][k] * fea[z][k] ----
    // 15 o-tiles of 16 split 4/4/4/3 over the 4 waves; single z-group of 16.
    const int lane = tid & 63, wave = tid >> 6;
    const int mcnt = (wave == 3) ? 3 : 4;
    const int zl = lane & 15;
    const int koff = (lane >> 4) * 8;

    f32x4 acc[4];
#pragma unroll
    for (int i = 0; i < 4; ++i) acc[i] = (f32x4){0.f, 0.f, 0.f, 0.f};

#pragma unroll
    for (int kc = 0; kc < 15; ++kc) {
        const int kg = kc * 32 + koff;
        bf16x8 bfr = *(const bf16x8*)&fea_s[zl][kg];
        const unsigned short* wp = w_bf + (size_t)(wave * 64 + zl) * K2C + kg;
#pragma unroll
        for (int mt = 0; mt < 4; ++mt) {
            if (mt < mcnt) {
                bf16x8 afr = *(const bf16x8*)(wp + (size_t)mt * 16 * K2C);
                acc[mt] = __builtin_amdgcn_mfma_f32_16x16x32_bf16(afr, bfr, acc[mt], 0, 0, 0);
            }
        }
    }

    const int vv = v0 + zl;
    const int rbase = (lane >> 4) * 4;
#pragma unroll
    for (int mt = 0; mt < 4; ++mt) {
        if (mt < mcnt) {
#pragma unroll
            for (int r = 0; r < 4; ++r) {
                int o = (wave * 4 + mt) * 16 + rbase + r;
                float y = acc[mt][r] * A_s[o] + B_s[o];
                y = y / (1.f + __expf(-y));
                outb[(size_t)o * V + vv] = y;
            }
        }
    }
}

extern "C" void kernel_launch(void* const* d_in, const int* in_sizes, int n_in,
                              void* d_out, int out_size, void* d_ws, size_t ws_size,
                              hipStream_t stream) {
    const float* features = (const float*)d_in[0];  // [B][C][N]
    const float* coords   = (const float*)d_in[1];  // [B][3][N]
    const float* conv_w   = (const float*)d_in[2];  // [240][480]
    const float* conv_b   = (const float*)d_in[3];
    const float* gamma    = (const float*)d_in[4];
    const float* beta     = (const float*)d_in[5];
    const float* mean     = (const float*)d_in[6];
    const float* var      = (const float*)d_in[7];

    float* out    = (float*)d_out;                    // [B][C][V]
    float* nc_out = out + (size_t)B * C * V;          // [B][3][N]

    char* ws = (char*)d_ws;
    size_t off = 0;
    auto carve = [&](size_t bytes) { char* p = ws + off; off += (bytes + 255) & ~(size_t)255; return p; };
    int*            hist   = (int*)carve((size_t)B * V * 4);          // 1 MB
    float*          stats  = (float*)carve(B * 4 * 4);
    int*            idxbuf = (int*)carve((size_t)B * N * 4);
    int*            starts = (int*)carve((size_t)B * V * 4);
    int*            cursor = (int*)carve((size_t)B * V * 4);
    int*            ptlist = (int*)carve((size_t)B * N * 4);
    unsigned short* w_bf   = (unsigned short*)carve((size_t)C * K2C * 2);
    unsigned short* featT  = (unsigned short*)carve((size_t)B * N * C * 2);  // 63 MB
    (void)off;

    init_stats_kernel<<<256 + B, 256, 0, stream>>>(coords, stats, hist, conv_w, w_bf);
    nc_idx_kernel<<<(B * N) / 256, 256, 0, stream>>>(coords, stats, nc_out, idxbuf, hist);
    prefix_kernel<<<B, 1024, 0, stream>>>(hist, starts, cursor);
    plist_kernel<<<(B * N) / 256, 256, 0, stream>>>(idxbuf, cursor, ptlist);
    transpose_kernel<<<dim3(N / 32, B), 256, 0, stream>>>(features, featT);
    column_kernel<<<dim3(NG, B), 256, 0, stream>>>(
        featT, ptlist, starts, hist, w_bf,
        conv_b, gamma, beta, mean, var, out);
    (void)in_sizes; (void)n_in; (void)out_size;
}